// Round 6
// baseline (334.676 us; speedup 1.0000x reference)
//
#include <hip/hip_runtime.h>
#include <hip/hip_bf16.h>

#define B_SZ  4
#define T_SEQ 4096
#define NE    2048
#define HD    128
#define NROWS (B_SZ * T_SEQ)   // 16384

typedef __attribute__((ext_vector_type(4))) float f32x4;
typedef __attribute__((ext_vector_type(8))) short s16x8;

__device__ __forceinline__ ushort f2bf(float f) {
    __hip_bfloat16 h = __float2bfloat16(f);
    return *reinterpret_cast<ushort*>(&h);
}
__device__ __forceinline__ unsigned int pk2(float a, float b) {
    return (unsigned int)f2bf(a) | ((unsigned int)f2bf(b) << 16);
}
__device__ __forceinline__ void gload_lds16(const void* g, void* l) {
    __builtin_amdgcn_global_load_lds(
        (const __attribute__((address_space(1))) unsigned int*)g,
        (__attribute__((address_space(3))) unsigned int*)l, 16, 0, 0);
}

// ---------------- K0: W fp32 [2048][128] -> wt bf16 [384][2048] (B^T layout) --------
// wt is written PRE-SWIZZLED: within each 64B (32-k) block of row r, the 16B slot
// s holds logical slot s ^ ((r>>1)&3).  qkv stages wt linearly into LDS and applies
// the same XOR on reads (rule 21: both-sides-or-neither).
__global__ __launch_bounds__(256) void wconv_kernel(
    const float* __restrict__ Wq, const float* __restrict__ Wk,
    const float* __restrict__ Wv, ushort* __restrict__ wt)
{
    __shared__ __align__(16) ushort tr[128][80];
    const int mat = blockIdx.y;
    const int k0  = blockIdx.x * 64;
    const float* W = (mat == 0) ? Wq : (mat == 1) ? Wk : Wv;
    const int tid = threadIdx.x;

    #pragma unroll
    for (int p = 0; p < 32; p++) {
        const int idx = p * 256 + tid;
        const int k = idx >> 7, h = idx & 127;
        tr[h][k] = f2bf(W[(size_t)(k0 + k) * HD + h]);
    }
    __syncthreads();
    const int h = tid >> 1, half = tid & 1;
    const int sw = (h >> 1) & 3;               // row = mat*128+h -> (row>>1)&3 == (h>>1)&3
    const uint4* src = (const uint4*)&tr[h][half * 32];
    uint4* dst = (uint4*)(wt + (size_t)(mat * HD + h) * NE + k0 + half * 32);
    #pragma unroll
    for (int j = 0; j < 4; j++) dst[j ^ sw] = src[j];
}

// ---------------- K1: qkv = x @ [Wq|Wk|Wv], MFMA bf16 ----------------
// 512 blocks x 256 threads: tile = 32 rows x 384 cols, BK=32, double-buffered.
// wt staged via linear global_load_lds (content pre-swizzled by wconv); x reg-staged
// fp32->bf16 with the same (row>>1)&3 slot swizzle.  Reads XOR the slot ->
// every 8 consecutive lanes hit 8 distinct bank groups: conflict-free b128.
// q outputs pre-scaled by 1/sqrt(128).
__global__ __launch_bounds__(256) void qkv_kernel(
    const float* __restrict__ x, const ushort* __restrict__ wt,
    ushort* __restrict__ q_b, ushort* __restrict__ k_b, ushort* __restrict__ vt)
{
    __shared__ __align__(16) ushort xa[2][32][32];   // 4 KB, slot-swizzled rows
    __shared__ __align__(16) ushort wb[2][384][32];  // 48 KB, slot-swizzled rows

    const int tid  = threadIdx.x;
    const int wave = tid >> 6, lane = tid & 63;
    const int nn   = lane & 15, quad = lane >> 4;
    const int rows0 = blockIdx.x * 32;
    const int mrow  = (wave & 1) * 16;      // wave's m-tile rows
    const int wc    = (wave >> 1) * 192;    // wave's column half
    const int rsw   = ((nn >> 1) & 3) << 4; // read-slot swizzle (row>>1)&3, rows=..+nn

    f32x4 acc[12];
    #pragma unroll
    for (int nt = 0; nt < 12; nt++) acc[nt] = (f32x4){0.f, 0.f, 0.f, 0.f};

    // ---- x staging: thread -> (row = tid>>3, 4-float k chunk), swizzled write ----
    const int xrow = tid >> 3, xoff = ((tid & 7) * 8) ^ (((xrow >> 1) & 3) << 4);
    const float* xp = x + (size_t)(rows0 + xrow) * NE + (tid & 7) * 4;
    float4 xr;
    auto load_x = [&](int kc) { xr = *(const float4*)(xp + kc); };
    auto write_x = [&](int buf) {
        uint2 w;
        w.x = pk2(xr.x, xr.y);
        w.y = pk2(xr.z, xr.w);
        *(uint2*)((char*)&xa[buf][xrow][0] + xoff) = w;
    };

    // ---- wt staging via global_load_lds (linear dest = base + tid*16) ----
    const char* wsrc0 = (const char*)wt + (size_t)(tid >> 2) * (NE * 2) + (tid & 3) * 16;
    char* wdst0 = (char*)wb + tid * 16;
    auto stage_w = [&](int buf, int kc) {
        #pragma unroll
        for (int rnd = 0; rnd < 6; rnd++)
            gload_lds16(wsrc0 + (size_t)rnd * 64 * (NE * 2) + kc * 2,
                        wdst0 + buf * 24576 + rnd * 4096);
    };

    load_x(0);
    stage_w(0, 0);
    write_x(0);
    asm volatile("s_waitcnt vmcnt(0)" ::: "memory");
    __syncthreads();

    for (int t = 0; t < 64; t++) {
        const int cb = t & 1;
        if (t + 1 < 64) { load_x((t + 1) * 32); stage_w(cb ^ 1, (t + 1) * 32); }
        const s16x8 af = *(const s16x8*)((const char*)&xa[cb][mrow + nn][0]
                                         + ((quad * 16) ^ rsw));
        #pragma unroll
        for (int nt = 0; nt < 12; nt++) {
            const s16x8 bf = *(const s16x8*)((const char*)&wb[cb][wc + nt * 16 + nn][0]
                                             + ((quad * 16) ^ rsw));
            acc[nt] = __builtin_amdgcn_mfma_f32_16x16x32_bf16(af, bf, acc[nt], 0, 0, 0);
        }
        if (t + 1 < 64) write_x(cb ^ 1);
        __syncthreads();
    }

    // epilogue: D row = quad*4+r (+mrow), col = nn (+wc+nt*16); q pre-scaled
    const float qscale = 0.08838834764831845f;   // 1/sqrt(128)
    #pragma unroll
    for (int nt = 0; nt < 12; nt++) {
        const int c = wc + nt * 16 + nn;
        #pragma unroll
        for (int r = 0; r < 4; r++) {
            const int grow = rows0 + mrow + quad * 4 + r;
            const float val = acc[nt][r];
            if (c < 128)       q_b[(size_t)grow * HD + c] = f2bf(val * qscale);
            else if (c < 256)  k_b[(size_t)grow * HD + (c - 128)] = f2bf(val);
            else               vt[(size_t)(c - 256) * NROWS + grow] = f2bf(val);
        }
    }
}

// ---------------- K2: causal flash attention, no-max softmax, MFMA row-sums ----
// 512 blocks (4 b x 128 q-tiles of 32 rows), 4 waves key-split, no main-loop
// barriers.  LDS 68KB -> 2 blocks/CU -> VGPR budget 256: K/V frag batches stay
// live.  pT stride 72 (144B = 9x16): b128 reads 16B-aligned + conflict-free.
__global__ __launch_bounds__(256) void attn_kernel(
    const ushort* __restrict__ q_b, const ushort* __restrict__ k_b,
    const ushort* __restrict__ vt, float* __restrict__ out)
{
    // union: pT [128][72] ushort (18.4KB, main loop) overlaps o_smem (merge)
    __shared__ __align__(16) char smem_raw[4 * 32 * 132 * 4];   // 67584 B
    float (*o_smem)[32][132] = reinterpret_cast<float (*)[32][132]>(smem_raw);
    ushort (*pT)[72]         = reinterpret_cast<ushort (*)[72]>(smem_raw);
    __shared__ float l_smem[4][32];

    const int bid = blockIdx.x;                 // 0..511
    const int xcd = bid & 7;
    const int b   = xcd >> 1;                   // 2 XCDs per batch (K/V L2 locality)
    const int qi  = 127 - (((bid >> 3) << 1) | (xcd & 1));   // heavy q-tiles first
    const int qrow0 = qi * 32;
    const size_t bT = (size_t)b * T_SEQ;

    const int tid  = threadIdx.x;
    const int wave = tid >> 6, lane = tid & 63;
    const int nn   = lane & 15, quad = lane >> 4;

    // Q fragments (pre-scaled by 1/sqrt(128)): 2 m-tiles x 4 k-steps
    s16x8 qfrag[2][4];
    #pragma unroll
    for (int m = 0; m < 2; m++)
        #pragma unroll
        for (int ks = 0; ks < 4; ks++)
            qfrag[m][ks] = *(const s16x8*)&q_b[(bT + qrow0 + m * 16 + nn) * HD + ks * 32 + quad * 8];

    s16x8 ones;
    #pragma unroll
    for (int j = 0; j < 8; j++) ones[j] = (short)0x3F80;   // bf16 1.0

    f32x4 o_acc[2][8], l_acc[2];
    #pragma unroll
    for (int m = 0; m < 2; m++) {
        #pragma unroll
        for (int nt = 0; nt < 8; nt++) o_acc[m][nt] = (f32x4){0.f, 0.f, 0.f, 0.f};
        l_acc[m] = (f32x4){0.f, 0.f, 0.f, 0.f};
    }

    const int ntiles = (qi >> 1) + 1;   // keys 0 .. qrow0+31

    for (int t = wave; t < ntiles; t += 4) {
        const int s0 = t * 64;
        const bool lastt = (t == ntiles - 1);   // only tile crossing the diagonal

        // K fragments -> regs (batched), then S = Q K^T (32 MFMA)
        s16x8 kf[4][4];
        #pragma unroll
        for (int ks = 0; ks < 4; ks++)
            #pragma unroll
            for (int n = 0; n < 4; n++)
                kf[ks][n] = *(const s16x8*)&k_b[(bT + s0 + n * 16 + nn) * HD + ks * 32 + quad * 8];

        f32x4 sa[2][4];
        #pragma unroll
        for (int m = 0; m < 2; m++)
            #pragma unroll
            for (int n = 0; n < 4; n++) sa[m][n] = (f32x4){0.f, 0.f, 0.f, 0.f};
        #pragma unroll
        for (int ks = 0; ks < 4; ks++)
            #pragma unroll
            for (int n = 0; n < 4; n++)
                #pragma unroll
                for (int m = 0; m < 2; m++)
                    sa[m][n] = __builtin_amdgcn_mfma_f32_16x16x32_bf16(
                        qfrag[m][ks], kf[ks][n], sa[m][n], 0, 0, 0);

        // V fragments issued now; latency hides under the exp phase
        s16x8 vb[8][2];
        #pragma unroll
        for (int nt = 0; nt < 8; nt++)
            #pragma unroll
            for (int kst = 0; kst < 2; kst++)
                vb[nt][kst] = *(const s16x8*)&vt[(size_t)(nt * 16 + nn) * NROWS + bT + s0 + kst * 32 + quad * 8];

        // P = exp(S); masked entries -> 0; write to wave-private pT rows
        #pragma unroll
        for (int m = 0; m < 2; m++)
            #pragma unroll
            for (int r = 0; r < 4; r++) {
                const int grow = qrow0 + m * 16 + quad * 4 + r;
                #pragma unroll
                for (int n = 0; n < 4; n++) {
                    const float p = (lastt && (s0 + n * 16 + nn > grow)) ? 0.0f : __expf(sa[m][n][r]);
                    pT[wave * 32 + m * 16 + quad * 4 + r][n * 16 + nn] = f2bf(p);
                }
            }

        // A-fragments of P
        s16x8 pf[2][2];
        #pragma unroll
        for (int m = 0; m < 2; m++)
            #pragma unroll
            for (int kst = 0; kst < 2; kst++)
                pf[m][kst] = *(const s16x8*)&pT[wave * 32 + m * 16 + nn][kst * 32 + quad * 8];

        // l += P @ ones (row sums in the matrix pipe)
        #pragma unroll
        for (int m = 0; m < 2; m++)
            #pragma unroll
            for (int kst = 0; kst < 2; kst++)
                l_acc[m] = __builtin_amdgcn_mfma_f32_16x16x32_bf16(pf[m][kst], ones, l_acc[m], 0, 0, 0);

        // O += P V (32 MFMA)
        #pragma unroll
        for (int nt = 0; nt < 8; nt++)
            #pragma unroll
            for (int kst = 0; kst < 2; kst++)
                #pragma unroll
                for (int m = 0; m < 2; m++)
                    o_acc[m][nt] = __builtin_amdgcn_mfma_f32_16x16x32_bf16(
                        pf[m][kst], vb[nt][kst], o_acc[m][nt], 0, 0, 0);
    }

    // ---- merge the 4 per-wave partials (plain sums) ----
    __syncthreads();   // all pT use done; safe to overwrite with o_smem

    #pragma unroll
    for (int m = 0; m < 2; m++) {
        if (nn == 0) {
            #pragma unroll
            for (int r = 0; r < 4; r++)
                l_smem[wave][m * 16 + quad * 4 + r] = l_acc[m][r];
        }
        #pragma unroll
        for (int nt = 0; nt < 8; nt++)
            #pragma unroll
            for (int r = 0; r < 4; r++)
                o_smem[wave][m * 16 + quad * 4 + r][nt * 16 + nn] = o_acc[m][nt][r];
    }

    __syncthreads();

    // wave w sums cols [w*32, w*32+32) over all 32 rows
    #pragma unroll
    for (int half = 0; half < 2; half++)
        #pragma unroll
        for (int rr = 0; rr < 4; rr++) {
            const int row = half * 16 + quad * 4 + rr;
            const float L = l_smem[0][row] + l_smem[1][row] + l_smem[2][row] + l_smem[3][row];
            const float invL = 1.0f / L;
            #pragma unroll
            for (int j = 0; j < 2; j++) {
                const int col = wave * 32 + j * 16 + nn;
                float s = 0.0f;
                #pragma unroll
                for (int p = 0; p < 4; p++) s += o_smem[p][row][col];
                out[(bT + qrow0 + row) * HD + col] = s * invL;
            }
        }
}

extern "C" void kernel_launch(void* const* d_in, const int* in_sizes, int n_in,
                              void* d_out, int out_size, void* d_ws, size_t ws_size,
                              hipStream_t stream) {
    const float* x  = (const float*)d_in[0];
    const float* Wq = (const float*)d_in[1];
    const float* Wk = (const float*)d_in[2];
    const float* Wv = (const float*)d_in[3];

    ushort* q_b = (ushort*)d_ws;                       // 4 MB
    ushort* k_b = q_b + (size_t)NROWS * HD;            // 4 MB
    ushort* vtp = k_b + (size_t)NROWS * HD;            // 4 MB (v transposed [h][row])
    ushort* wt  = vtp + (size_t)HD * NROWS;            // 1.5 MB ([384][2048] bf16)

    wconv_kernel<<<dim3(32, 3), dim3(256), 0, stream>>>(Wq, Wk, Wv, wt);
    qkv_kernel<<<dim3(512), dim3(256), 0, stream>>>(x, wt, q_b, k_b, vtp);
    attn_kernel<<<dim3(512), dim3(256), 0, stream>>>(q_b, k_b, vtp, (float*)d_out);
}